// Round 5
// baseline (216.149 us; speedup 1.0000x reference)
//
#include <hip/hip_runtime.h>

#define PI_D 3.141592653589793238462643383279502884

// x (8,256,256,64) f32 -> out (8,256,256,64) f32.
// Forward padded FFT (272,272,80) pad=8; x_ft = Re(F)-Im(F) on 4 corner blocks.
// Inverse (256,256,64); out = Re(G)-Im(G).
// Re-Im collapse: Re-Im(sum a*w) = sum a.x*P + a.y*Qm, P=c-s, Qm=-(c+s).

// ---------------- twiddle tables (double-precision build) ----------------
__global__ void k_tables(float2* __restrict__ wt, float2* __restrict__ wxy,
                         float2* __restrict__ vt, float2* __restrict__ vxy,
                         float2* __restrict__ pqf, float2* __restrict__ pqi) {
  int t = blockIdx.x * blockDim.x + threadIdx.x;
  if (t < 64 * 16) {  // wt[n3][k3] = exp(-2pi i k3 (n3+8)/80)
    int n3 = t >> 4, k3 = t & 15;
    int ph = (k3 * (n3 + 8)) % 80;
    double a = -2.0 * PI_D * (double)ph / 80.0;
    wt[t] = make_float2((float)cos(a), (float)sin(a));
  }
  if (t < 256 * 32) {  // wxy[n][k] = exp(-2pi i kk (n+8)/272), kk = k<16 ? k : 240+k
    int n = t >> 5, k = t & 31;
    int kk = (k < 16) ? k : (240 + k);
    int ph = (kk * (n + 8)) % 272;
    double a = -2.0 * PI_D * (double)ph / 272.0;
    double c = cos(a), s = sin(a);
    wxy[t] = make_float2((float)c, (float)s);
    pqf[t] = make_float2((float)(c - s), (float)(-(c + s)));  // P, Qm (forward)
  }
  if (t < 16 * 64) {  // vt[k3][n3] = exp(+2pi i k3 n3 / 64)
    int k3 = t >> 6, n3 = t & 63;
    int ph = (k3 * n3) & 63;
    double a = 2.0 * PI_D * (double)ph / 64.0;
    vt[t] = make_float2((float)cos(a), (float)sin(a));
  }
  if (t < 256 * 32) {  // vxy[n][k] = exp(+2pi i k n / 256); pqi scaled by 1/N (exact pow2)
    int n = t >> 5, k = t & 31;
    int ph = (k * n) & 255;
    double a = 2.0 * PI_D * (double)ph / 256.0;
    double c = cos(a), s = sin(a);
    vxy[t] = make_float2((float)c, (float)s);
    const double inv = 1.0 / 4194304.0;  // 1/(256*256*64)
    pqi[t] = make_float2((float)((c - s) * inv), (float)((-(c + s)) * inv));
  }
}

// ---------------- Step A: T-axis forward DFT (LDS-transposed, coalesced) ----------------
// A[b,n1,n2,k3] = sum_n3 x[b,n1,n2,n3] * wt[n3][k3]
__global__ __launch_bounds__(256) void k_fft_t(const float* __restrict__ x,
                                               float2* __restrict__ A,
                                               const float2* __restrict__ wt) {
  __shared__ float sX[64][65];   // 64 rows x 64 cols, +1 pad
  __shared__ float2 swt[1024];   // wt[64][16]
  long blk = blockIdx.x;         // 8192 blocks x 64 rows
  int tid = threadIdx.x;
  const float4* xg = (const float4*)(x + blk * 4096);
#pragma unroll
  for (int e = 0; e < 4; e++) {
    int idx = tid + e * 256;  // 1024 float4, fully coalesced
    float4 v = xg[idx];
    int r = idx >> 4, c = (idx & 15) * 4;
    sX[r][c] = v.x; sX[r][c + 1] = v.y; sX[r][c + 2] = v.z; sX[r][c + 3] = v.w;
  }
#pragma unroll
  for (int e = 0; e < 4; e++) swt[tid + e * 256] = wt[tid + e * 256];
  __syncthreads();
  int r = tid >> 2, q = (tid & 3) * 4;  // row, k-quad
  float2 a0 = {0,0}, a1 = {0,0}, a2 = {0,0}, a3 = {0,0};
#pragma unroll 8
  for (int n3 = 0; n3 < 64; n3++) {
    float xv = sX[r][n3];
    const float2* wr = &swt[n3 * 16 + q];
    float2 w0 = wr[0], w1 = wr[1], w2 = wr[2], w3 = wr[3];
    a0.x = fmaf(xv, w0.x, a0.x); a0.y = fmaf(xv, w0.y, a0.y);
    a1.x = fmaf(xv, w1.x, a1.x); a1.y = fmaf(xv, w1.y, a1.y);
    a2.x = fmaf(xv, w2.x, a2.x); a2.y = fmaf(xv, w2.y, a2.y);
    a3.x = fmaf(xv, w3.x, a3.x); a3.y = fmaf(xv, w3.y, a3.y);
  }
  float4* Ao = (float4*)(A + (blk * 64 + r) * 16 + q);
  Ao[0] = make_float4(a0.x, a0.y, a1.x, a1.y);
  Ao[1] = make_float4(a2.x, a2.y, a3.x, a3.y);
}

// ---------------- Step B: Y-axis forward DFT (LDS-chunked twiddles) ----------------
// Bm[b,n1,k2,k3] = sum_n2 A[b,n1,n2,k3] * wxy[n2][k2]
__global__ __launch_bounds__(256) void k_fft_y(const float2* __restrict__ A,
                                               float2* __restrict__ Bm,
                                               const float2* __restrict__ wxy) {
  __shared__ float2 sA[4096];  // [n2][k3] 32 KB
  __shared__ float2 sW[2048];  // [64 n2][32 k2] chunk, 16 KB
  int bn1 = blockIdx.x;
  int tid = threadIdx.x;
  const float4* Ag = (const float4*)(A + (long)bn1 * 4096);
  float4* sA4 = (float4*)sA;
#pragma unroll
  for (int e = 0; e < 8; e++) sA4[tid + e * 256] = Ag[tid + e * 256];
  int k2 = tid >> 3, p = (tid & 7) * 2;  // two k3 per thread: p, p+1
  float2 r0 = {0,0}, r1 = {0,0};
  const float4* wg4 = (const float4*)wxy;
  float4* sW4 = (float4*)sW;
  for (int ch = 0; ch < 4; ch++) {
    __syncthreads();  // also covers the sA staging before ch 0
#pragma unroll
    for (int e = 0; e < 4; e++) sW4[tid + e * 256] = wg4[ch * 1024 + tid + e * 256];
    __syncthreads();
#pragma unroll 4
    for (int t = 0; t < 64; t++) {
      float4 av = *(const float4*)&sA[(ch * 64 + t) * 16 + p];
      float2 w = sW[t * 32 + k2];
      r0.x = fmaf(av.x, w.x, r0.x); r0.x = fmaf(-av.y, w.y, r0.x);
      r0.y = fmaf(av.x, w.y, r0.y); r0.y = fmaf(av.y, w.x, r0.y);
      r1.x = fmaf(av.z, w.x, r1.x); r1.x = fmaf(-av.w, w.y, r1.x);
      r1.y = fmaf(av.z, w.y, r1.y); r1.y = fmaf(av.w, w.x, r1.y);
    }
  }
  float4* Bo = (float4*)(Bm + (long)bn1 * 512 + k2 * 16 + p);
  *Bo = make_float4(r0.x, r0.y, r1.x, r1.y);
}

// ---------------- Step C: X-axis forward DFT (all-LDS, Re-Im collapsed) ----------------
__global__ __launch_bounds__(512) void k_fft_x(
    const float2* __restrict__ Bm, float* __restrict__ y,
    const float2* __restrict__ pqf,
    const float* __restrict__ w_tl, const float* __restrict__ w_tr,
    const float* __restrict__ w_bl, const float* __restrict__ w_br,
    const float* __restrict__ b_tl, const float* __restrict__ b_tr,
    const float* __restrict__ b_bl, const float* __restrict__ b_br) {
  __shared__ float2 sB[4096];   // [n1][k3] 32 KB
  __shared__ float2 sPQ[8192];  // full pqf table, 64 KB  (96 KB total, 1 block/CU)
  int b = blockIdx.x >> 5, k2 = blockIdx.x & 31;
  int tid = threadIdx.x;
  for (int i = tid; i < 4096; i += 512) {
    sB[i] = Bm[((long)(b * 256 + (i >> 4)) * 32 + k2) * 16 + (i & 15)];
  }
  const float4* pq4 = (const float4*)pqf;
  float4* sPQ4 = (float4*)sPQ;
#pragma unroll
  for (int e = 0; e < 8; e++) sPQ4[tid + e * 512] = pq4[tid + e * 512];
  __syncthreads();
  int k1 = tid >> 4, k3 = tid & 15;
  float acc = 0.f;
#pragma unroll 8
  for (int n1 = 0; n1 < 256; n1++) {
    float2 a = sB[n1 * 16 + k3];
    float2 w = sPQ[n1 * 32 + k1];  // (P, Qm)
    acc = fmaf(a.x, w.x, acc);
    acc = fmaf(a.y, w.y, acc);
  }
  const float* wsel = (k1 < 16) ? ((k2 < 16) ? w_tl : w_bl) : ((k2 < 16) ? w_tr : w_br);
  const float* bsel = (k1 < 16) ? ((k2 < 16) ? b_tl : b_bl) : ((k2 < 16) ? b_tr : b_br);
  int idx = ((k1 & 15) * 16 + (k2 & 15)) * 16 + k3;
  y[((b * 32 + k1) * 32 + k2) * 16 + k3] = fmaf(acc, wsel[idx], bsel[idx]);
}

// ---------------- Steps D+E fused: T-axis then Y-axis inverse DFT (GEMM form) ----------------
// D[k2,n3] = sum_k3 y[b,k1,k2,k3]*vt[k3][n3]  (recomputed per block in LDS)
// E[b,k1,n2,n3] = sum_k2 D[k2,n3] * vxy[n2][k2]
// Block: (b,k1,half); 128 n2 x 64 n3 output tile. Thread: 4 n2 x 8 complex n3.
__global__ __launch_bounds__(256) void k_inv_te(const float* __restrict__ y,
                                                float2* __restrict__ E,
                                                const float2* __restrict__ vt,
                                                const float2* __restrict__ vxy) {
  __shared__ float sy[512];      // y[b,k1,:,:]  32x16
  __shared__ float2 svt[1024];   // vt[16][64]
  __shared__ float sD[32][132];  // D re/im interleaved: [k2][2*n3], pad
  __shared__ float sV[128][66];  // V c/s interleaved: [n2 local][2*k2], pad
  int blk = blockIdx.x;          // bk1*2 + h
  int h = blk & 1, bk1 = blk >> 1;
  int tid = threadIdx.x;
  ((float2*)sy)[tid] = ((const float2*)(y + (long)bk1 * 512))[tid];
#pragma unroll
  for (int e = 0; e < 4; e++) svt[tid + e * 256] = vt[tid + e * 256];
#pragma unroll
  for (int e = 0; e < 16; e++) {  // stage V panel: 128 rows x 32 k2
    int q = tid + e * 256;
    int n2l = q >> 5, k2 = q & 31;
    float2 v = vxy[(h * 128 + n2l) * 32 + k2];
    *(float2*)&sV[n2l][2 * k2] = v;
  }
  __syncthreads();
#pragma unroll
  for (int e = 0; e < 8; e++) {  // compute D (32x64 complex)
    int idx = tid + e * 256;
    int k2 = idx >> 6, n3i = idx & 63;
    float ax = 0.f, ay = 0.f;
#pragma unroll
    for (int k3 = 0; k3 < 16; k3++) {
      float yv = sy[k2 * 16 + k3];
      float2 v = svt[k3 * 64 + n3i];
      ax = fmaf(yv, v.x, ax); ay = fmaf(yv, v.y, ay);
    }
    *(float2*)&sD[k2][2 * n3i] = make_float2(ax, ay);
  }
  __syncthreads();
  int rg = tid >> 3, tn = tid & 7;  // rows n2l = rg*4+i; cols n3 = tn*8+j
  float acc[4][16];
#pragma unroll
  for (int i = 0; i < 4; i++)
#pragma unroll
    for (int j = 0; j < 16; j++) acc[i][j] = 0.f;
#pragma unroll 2
  for (int k2 = 0; k2 < 32; k2++) {
    float4 d0 = *(const float4*)&sD[k2][tn * 16];
    float4 d1 = *(const float4*)&sD[k2][tn * 16 + 4];
    float4 d2 = *(const float4*)&sD[k2][tn * 16 + 8];
    float4 d3 = *(const float4*)&sD[k2][tn * 16 + 12];
#pragma unroll
    for (int i = 0; i < 4; i++) {
      float2 v = *(const float2*)&sV[rg * 4 + i][2 * k2];
      float c = v.x, s = v.y;
      acc[i][0]  = fmaf(c, d0.x, fmaf(-s, d0.y, acc[i][0]));
      acc[i][1]  = fmaf(c, d0.y, fmaf( s, d0.x, acc[i][1]));
      acc[i][2]  = fmaf(c, d0.z, fmaf(-s, d0.w, acc[i][2]));
      acc[i][3]  = fmaf(c, d0.w, fmaf( s, d0.z, acc[i][3]));
      acc[i][4]  = fmaf(c, d1.x, fmaf(-s, d1.y, acc[i][4]));
      acc[i][5]  = fmaf(c, d1.y, fmaf( s, d1.x, acc[i][5]));
      acc[i][6]  = fmaf(c, d1.z, fmaf(-s, d1.w, acc[i][6]));
      acc[i][7]  = fmaf(c, d1.w, fmaf( s, d1.z, acc[i][7]));
      acc[i][8]  = fmaf(c, d2.x, fmaf(-s, d2.y, acc[i][8]));
      acc[i][9]  = fmaf(c, d2.y, fmaf( s, d2.x, acc[i][9]));
      acc[i][10] = fmaf(c, d2.z, fmaf(-s, d2.w, acc[i][10]));
      acc[i][11] = fmaf(c, d2.w, fmaf( s, d2.z, acc[i][11]));
      acc[i][12] = fmaf(c, d3.x, fmaf(-s, d3.y, acc[i][12]));
      acc[i][13] = fmaf(c, d3.y, fmaf( s, d3.x, acc[i][13]));
      acc[i][14] = fmaf(c, d3.z, fmaf(-s, d3.w, acc[i][14]));
      acc[i][15] = fmaf(c, d3.w, fmaf( s, d3.z, acc[i][15]));
    }
  }
#pragma unroll
  for (int i = 0; i < 4; i++) {
    int n2g = h * 128 + rg * 4 + i;
    float4* dst = (float4*)&E[((long)bk1 * 256 + n2g) * 64 + tn * 8];
    dst[0] = make_float4(acc[i][0], acc[i][1], acc[i][2], acc[i][3]);
    dst[1] = make_float4(acc[i][4], acc[i][5], acc[i][6], acc[i][7]);
    dst[2] = make_float4(acc[i][8], acc[i][9], acc[i][10], acc[i][11]);
    dst[3] = make_float4(acc[i][12], acc[i][13], acc[i][14], acc[i][15]);
  }
}

// ---------------- Step F: X-axis inverse DFT as full-column GEMM ----------------
// Per batch: out[256 n1, 16384 col] = W[256, 64] x D[64, 16384]
//   W[n1][2k1]=P*invN, W[n1][2k1+1]=Qm*invN;  D[2k1][col]=Ex, D[2k1+1][col]=Ey.
// Block: ALL 256 n1 x 64 cols (E read once). Thread: 8x8 accumulator.
__global__ __launch_bounds__(256) void k_ifft_x(const float2* __restrict__ E,
                                                float* __restrict__ out,
                                                const float2* __restrict__ pqi) {
  __shared__ float sW[64][256];  // [kk][n1] 64 KB
  __shared__ float sD[64][64];   // [kk][col] 16 KB   (80 KB total -> 2 blocks/CU)
  int blk = blockIdx.x;          // b*256 + tc
  int tc = blk & 255, b = blk >> 8;
  int tid = threadIdx.x;
  // stage W: thread owns n1 = tid; streams its 16 consecutive float4 of pqi
  {
    const float4* pq4 = (const float4*)pqi;
#pragma unroll
    for (int r = 0; r < 16; r++) {
      float4 v = pq4[tid * 16 + r];  // (P[2r], Qm[2r], P[2r+1], Qm[2r+1])
      sW[4 * r][tid] = v.x; sW[4 * r + 1][tid] = v.y;
      sW[4 * r + 2][tid] = v.z; sW[4 * r + 3][tid] = v.w;
    }
  }
  // stage D: 512 tasks, 2 float4 (4 complex) each; single pass over E slice
  {
    const float4* Eg = (const float4*)E;
#pragma unroll
    for (int e = 0; e < 2; e++) {
      int tq = tid + e * 256;
      int k1 = tq >> 4, cq = tq & 15;
      const float4* src = Eg + ((long)(b * 32 + k1) * 8192) + tc * 32 + 2 * cq;
      float4 v0 = src[0], v1 = src[1];
      *(float4*)&sD[2 * k1][4 * cq]     = make_float4(v0.x, v0.z, v1.x, v1.z);
      *(float4*)&sD[2 * k1 + 1][4 * cq] = make_float4(v0.y, v0.w, v1.y, v1.w);
    }
  }
  __syncthreads();
  int tm = tid >> 3, tn = tid & 7;  // rows n1 = tm*8+i, cols tc*64 + tn*8+j
  float acc[8][8];
#pragma unroll
  for (int i = 0; i < 8; i++)
#pragma unroll
    for (int j = 0; j < 8; j++) acc[i][j] = 0.f;
#pragma unroll 2
  for (int kk = 0; kk < 64; kk++) {
    float4 wa = *(const float4*)&sW[kk][tm * 8];
    float4 wb = *(const float4*)&sW[kk][tm * 8 + 4];
    float4 da = *(const float4*)&sD[kk][tn * 8];
    float4 db = *(const float4*)&sD[kk][tn * 8 + 4];
    float w[8] = {wa.x, wa.y, wa.z, wa.w, wb.x, wb.y, wb.z, wb.w};
    float d[8] = {da.x, da.y, da.z, da.w, db.x, db.y, db.z, db.w};
#pragma unroll
    for (int i = 0; i < 8; i++)
#pragma unroll
      for (int j = 0; j < 8; j++) acc[i][j] = fmaf(w[i], d[j], acc[i][j]);
  }
  float* ob = out + (long)b * 4194304 + (long)(tm * 8) * 16384 + tc * 64 + tn * 8;
#pragma unroll
  for (int i = 0; i < 8; i++) {
    float4* o = (float4*)(ob + (long)i * 16384);
    o[0] = make_float4(acc[i][0], acc[i][1], acc[i][2], acc[i][3]);
    o[1] = make_float4(acc[i][4], acc[i][5], acc[i][6], acc[i][7]);
  }
}

extern "C" void kernel_launch(void* const* d_in, const int* in_sizes, int n_in,
                              void* d_out, int out_size, void* d_ws, size_t ws_size,
                              hipStream_t stream) {
  const float* x    = (const float*)d_in[0];
  const float* w_tl = (const float*)d_in[1];
  const float* w_tr = (const float*)d_in[2];
  const float* w_bl = (const float*)d_in[3];
  const float* w_br = (const float*)d_in[4];
  const float* b_tl = (const float*)d_in[5];
  const float* b_tr = (const float*)d_in[6];
  const float* b_bl = (const float*)d_in[7];
  const float* b_br = (const float*)d_in[8];
  float* out = (float*)d_out;
  char* ws = (char*)d_ws;

  // Workspace layout (bytes):
  float2* Bm  = (float2*)(ws + 0);          //  8,388,608  (8,256,32,16) c64
  float*  y   = (float*)(ws + 8388608);     //  2,097,152  (8,32,32,16)  f32
  float2* E   = (float2*)(ws + 10485760);   // 33,554,432  (8,32,256,64) c64
  float2* WT  = (float2*)(ws + 44040192);   //  8 KB
  float2* WXY = (float2*)(ws + 44048384);   // 64 KB
  float2* VT  = (float2*)(ws + 44113920);   //  8 KB
  float2* VXY = (float2*)(ws + 44122112);   // 64 KB
  float2* PQF = (float2*)(ws + 44187648);   // 64 KB
  float2* PQI = (float2*)(ws + 44253184);   // 64 KB  (end ~44.3 MB)
  // Stage-A output (67 MB) aliases d_out; dead before k_ifft_x writes out.
  float2* A = (float2*)d_out;

  k_tables<<<32, 256, 0, stream>>>(WT, WXY, VT, VXY, PQF, PQI);
  k_fft_t<<<8192, 256, 0, stream>>>(x, A, WT);
  k_fft_y<<<2048, 256, 0, stream>>>(A, Bm, WXY);
  k_fft_x<<<256, 512, 0, stream>>>(Bm, y, PQF, w_tl, w_tr, w_bl, w_br,
                                   b_tl, b_tr, b_bl, b_br);
  k_inv_te<<<512, 256, 0, stream>>>(y, E, VT, VXY);
  k_ifft_x<<<2048, 256, 0, stream>>>(E, out, PQI);
}